// Round 4
// baseline (214.220 us; speedup 1.0000x reference)
//
#include <hip/hip_runtime.h>
#include <float.h>
#include <math.h>

#define NSAMPLE 8192
#define KSEL 9          // K+1: keep 9 smallest incl. self
#define KNN 8
#define BLK 256
#define EPS_F 1e-12f

#define ROWBLKS (NSAMPLE / BLK)      // 32 row-blocks
#define BCHUNKS 8                    // bound phase: 8 chunks x 256 = 2048-cand subset
#define FCHUNKS 32                   // filter phase: 32 chunks x 256 = full scan
#define CHUNK 256
#define SLOTS 768                    // survivor cap per row (exp ~170)
#define IDX_MASK 0x1FFFu             // low 13 bits = candidate index
#define VAL_MASK 0xFFFFE000u         // high 19 bits = d2 (sign+exp+10 mantissa)
#define SCALE (1.0f / (float)(NSAMPLE * KNN * 3))

__device__ __forceinline__ unsigned umn(unsigned a, unsigned b) { return a < b ? a : b; }
__device__ __forceinline__ unsigned umx(unsigned a, unsigned b) { return a > b ? a : b; }

// Branchless insert of x into descending-sorted s[0..8] (s[0]=worst, s[8]=best).
__device__ __forceinline__ void insert9(unsigned s[KSEL], unsigned x)
{
#pragma unroll
    for (int k = 0; k < KSEL - 1; ++k)
        s[k] = umx(s[k + 1], umn(x, s[k]));
    s[KSEL - 1] = umn(x, s[KSEL - 1]);
}

// Packed (d2 | idx). d2 clamped >= 0 so self packs minimal (sq-form can go
// slightly negative for self; losing self from the filter would be WRONG).
__device__ __forceinline__ unsigned pack_d2(float d2, int gidx)
{
    return (__float_as_uint(fmaxf(d2, 0.0f)) & VAL_MASK) | (unsigned)gidx;
}

// ---------------------------------------------------------------------------
// Kernel 1: gather sampled means/sh0 (w of sm4 = |mean|^2); init bound/cnt/out.
// ---------------------------------------------------------------------------
__global__ __launch_bounds__(BLK) void gather_k(
    const float* __restrict__ means, const float* __restrict__ sh0,
    const int* __restrict__ idx,
    float4* __restrict__ sm4, float4* __restrict__ ss4,
    unsigned* __restrict__ bound, unsigned* __restrict__ cnt,
    float* __restrict__ out)
{
    int i = blockIdx.x * BLK + threadIdx.x;
    if (i == 0) out[0] = 0.0f;
    if (i >= NSAMPLE) return;
    bound[i] = 0xFFFFFFFFu;
    cnt[i] = 0u;
    int id = idx[i];
    const float* m = means + 3 * (long long)id;
    const float* s = sh0 + 3 * (long long)id;
    float mx = m[0], my = m[1], mz = m[2];
    sm4[i] = make_float4(mx, my, mz, fmaf(mx, mx, fmaf(my, my, mz * mz)));
    ss4[i] = make_float4(s[0], s[1], s[2], 0.0f);
}

// ---------------------------------------------------------------------------
// Kernel 2: bound. Each thread owns a row, scans one 256-cand chunk of the
// first 2048 candidates with full top-9; chunk's 9th (s[0]) is a valid upper
// bound on the global 9th (packed order); atomicMin across chunks.
// ---------------------------------------------------------------------------
__global__ __launch_bounds__(BLK) void bound_k(
    const float4* __restrict__ sm4, unsigned* __restrict__ bound)
{
    const int t = threadIdx.x;
    const int rowblk = blockIdx.x & (ROWBLKS - 1);
    const int c = blockIdx.x / ROWBLKS;          // 0..BCHUNKS-1
    const int row = rowblk * BLK + t;
    const int cbase = c * CHUNK;

    __shared__ float4 cand[CHUNK];
    cand[t] = sm4[cbase + t];

    float4 p = sm4[row];
    float n2x = -2.0f * p.x, n2y = -2.0f * p.y, n2z = -2.0f * p.z;
    float sp = p.w;
    __syncthreads();

    unsigned s[KSEL];
#pragma unroll
    for (int k = 0; k < KSEL; ++k) s[k] = 0xFFFFFFFFu;

#pragma unroll 8
    for (int j = 0; j < CHUNK; ++j) {
        float4 q = cand[j];
        float d2 = fmaf(n2x, q.x, fmaf(n2y, q.y, fmaf(n2z, q.z, sp + q.w)));
        insert9(s, pack_d2(d2, cbase + j));
    }
    atomicMin(&bound[row], s[0]);   // s[0] = 9th smallest of this chunk
}

// ---------------------------------------------------------------------------
// Kernel 3: filter. Full 8192-candidate rescan, ~10 inst/candidate, append
// survivors (x <= bound, inclusive) to per-row list. All true top-9 survive.
// ---------------------------------------------------------------------------
__global__ __launch_bounds__(BLK) void filter_k(
    const float4* __restrict__ sm4, const unsigned* __restrict__ bound,
    unsigned* __restrict__ cnt, unsigned* __restrict__ surv)
{
    const int t = threadIdx.x;
    const int rowblk = blockIdx.x & (ROWBLKS - 1);
    const int c = blockIdx.x / ROWBLKS;          // 0..FCHUNKS-1
    const int row = rowblk * BLK + t;
    const int cbase = c * CHUNK;

    __shared__ float4 cand[CHUNK];
    cand[t] = sm4[cbase + t];

    float4 p = sm4[row];
    float n2x = -2.0f * p.x, n2y = -2.0f * p.y, n2z = -2.0f * p.z;
    float sp = p.w;
    unsigned b = bound[row];
    unsigned* rowsurv = surv + (unsigned)row * SLOTS;
    __syncthreads();

#pragma unroll 8
    for (int j = 0; j < CHUNK; ++j) {
        float4 q = cand[j];
        float d2 = fmaf(n2x, q.x, fmaf(n2y, q.y, fmaf(n2z, q.z, sp + q.w)));
        unsigned x = pack_d2(d2, cbase + j);
        if (x <= b) {
            unsigned pos = atomicAdd(&cnt[row], 1u);
            if (pos < SLOTS) rowsurv[pos] = x;
        }
    }
}

// ---------------------------------------------------------------------------
// Kernel 4: select + loss. One thread per row: exact top-9 over ~170
// survivors, drop min (self / zero-dup), exact-d2 loss terms, wave-reduce,
// one atomicAdd per wave.
// ---------------------------------------------------------------------------
__global__ __launch_bounds__(64) void select_k(
    const unsigned* __restrict__ surv, const unsigned* __restrict__ cnt,
    const float4* __restrict__ sm4, const float4* __restrict__ ss4,
    float* __restrict__ out)
{
    const int r = blockIdx.x * 64 + threadIdx.x;
    const unsigned n = umn(cnt[r], SLOTS);
    const unsigned* base = surv + (unsigned)r * SLOTS;

    unsigned s[KSEL];
#pragma unroll
    for (int k = 0; k < KSEL; ++k) s[k] = 0xFFFFFFFFu;

#pragma unroll 8
    for (unsigned e = 0; e < n; ++e)
        insert9(s, base[e]);

    // s[8] = global min (self, or identical-coordinate dup whose term is 0
    // either way) -> dropped. s[0..7] = the 8 neighbors.
    float4 pm = sm4[r];
    float4 ps = ss4[r];
    float acc = 0.0f;
#pragma unroll
    for (int k = 0; k < KNN; ++k) {
        int j = (int)(s[k] & IDX_MASK);
        float4 qm = sm4[j];
        float dx = pm.x - qm.x, dy = pm.y - qm.y, dz = pm.z - qm.z;
        float d2 = fmaf(dx, dx, fmaf(dy, dy, dz * dz));
        float d = sqrtf(fmaxf(d2, EPS_F));
        float w = expf(-d);
        float4 qs = ss4[j];
        float ax = ps.x - qs.x, ay = ps.y - qs.y, az = ps.z - qs.z;
        acc += w * (ax * ax + ay * ay + az * az);
    }
    acc *= SCALE;

    for (int off = 32; off > 0; off >>= 1) acc += __shfl_down(acc, off);
    if (threadIdx.x == 0) atomicAdd(out, acc);
}

// ---------------------------------------------------------------------------
extern "C" void kernel_launch(void* const* d_in, const int* in_sizes, int n_in,
                              void* d_out, int out_size, void* d_ws, size_t ws_size,
                              hipStream_t stream)
{
    const float* means = (const float*)d_in[0];
    const float* sh0   = (const float*)d_in[1];
    const int*   idx   = (const int*)d_in[2];

    char* ws = (char*)d_ws;
    float4*   sm4   = (float4*)ws;                              // 128 KB
    float4*   ss4   = (float4*)(ws + NSAMPLE * 16);             // 128 KB
    unsigned* bound = (unsigned*)(ws + 2 * NSAMPLE * 16);       // 32 KB
    unsigned* cnt   = bound + NSAMPLE;                          // 32 KB
    unsigned* surv  = cnt + NSAMPLE;                            // 24 MB

    gather_k<<<NSAMPLE / BLK, BLK, 0, stream>>>(means, sh0, idx, sm4, ss4,
                                                bound, cnt, (float*)d_out);
    bound_k<<<BCHUNKS * ROWBLKS, BLK, 0, stream>>>(sm4, bound);
    filter_k<<<FCHUNKS * ROWBLKS, BLK, 0, stream>>>(sm4, bound, cnt, surv);
    select_k<<<NSAMPLE / 64, 64, 0, stream>>>(surv, cnt, sm4, ss4,
                                              (float*)d_out);
}

// Round 5
// 146.968 us; speedup vs baseline: 1.4576x; 1.4576x over previous
//
#include <hip/hip_runtime.h>
#include <float.h>
#include <math.h>

#define NSAMPLE 8192
#define KSEL 9          // K+1: keep 9 smallest incl. self
#define KNN 8
#define BLK 256
#define EPS_F 1e-12f

#define ROWBLKS (NSAMPLE / BLK)      // 32 row-blocks
#define BCHUNKS 8                    // bound phase: 8 chunks x 256 = 2048-cand subset
#define FCHUNKS 32                   // filter phase: full scan
#define CHUNK 256
#define CAP 24                       // survivor slots per (row, chunk); mean ~5
#define IDX_MASK 0x1FFFu             // low 13 bits = candidate index
#define VAL_MASK 0xFFFFE000u         // high 19 bits = d2 (sign+exp+10 mantissa)
#define SCALE (1.0f / (float)(NSAMPLE * KNN * 3))

#define SUBS 8                       // select: threads per row
#define CPT (FCHUNKS / SUBS)         // 4 chunks per select thread
#define ROWS_PB 32                   // select: rows per block
#define LROW 73                      // LDS row stride (8*9=72 +1 pad, kills 8-way conflict)

__device__ __forceinline__ unsigned umn(unsigned a, unsigned b) { return a < b ? a : b; }
__device__ __forceinline__ unsigned umx(unsigned a, unsigned b) { return a > b ? a : b; }

// Branchless insert of x into descending-sorted s[0..8] (s[0]=worst, s[8]=best).
__device__ __forceinline__ void insert9(unsigned s[KSEL], unsigned x)
{
#pragma unroll
    for (int k = 0; k < KSEL - 1; ++k)
        s[k] = umx(s[k + 1], umn(x, s[k]));
    s[KSEL - 1] = umn(x, s[KSEL - 1]);
}

// Packed (d2 | idx). d2 clamped >= 0 so self packs minimal (sq-form may go
// slightly negative for self; self must always pass the filter).
__device__ __forceinline__ unsigned pack_d2(float d2, int gidx)
{
    return (__float_as_uint(fmaxf(d2, 0.0f)) & VAL_MASK) | (unsigned)gidx;
}

// ---------------------------------------------------------------------------
// Kernel 1: gather sampled means/sh0 (w of sm4 = |mean|^2); init bound/out.
// ---------------------------------------------------------------------------
__global__ __launch_bounds__(BLK) void gather_k(
    const float* __restrict__ means, const float* __restrict__ sh0,
    const int* __restrict__ idx,
    float4* __restrict__ sm4, float4* __restrict__ ss4,
    unsigned* __restrict__ bound, float* __restrict__ out)
{
    int i = blockIdx.x * BLK + threadIdx.x;
    if (i == 0) out[0] = 0.0f;
    if (i >= NSAMPLE) return;
    bound[i] = 0xFFFFFFFFu;
    int id = idx[i];
    const float* m = means + 3 * (long long)id;
    const float* s = sh0 + 3 * (long long)id;
    float mx = m[0], my = m[1], mz = m[2];
    sm4[i] = make_float4(mx, my, mz, fmaf(mx, mx, fmaf(my, my, mz * mz)));
    ss4[i] = make_float4(s[0], s[1], s[2], 0.0f);
}

// ---------------------------------------------------------------------------
// Kernel 2: bound. Thread owns a row, scans one 256-cand chunk (8 chunks =
// 2048-cand subset) with full top-9; chunk's 9th (s[0]) upper-bounds the
// global 9th (packed order); atomicMin across chunks.
// ---------------------------------------------------------------------------
__global__ __launch_bounds__(BLK) void bound_k(
    const float4* __restrict__ sm4, unsigned* __restrict__ bound)
{
    const int t = threadIdx.x;
    const int rowblk = blockIdx.x & (ROWBLKS - 1);
    const int c = blockIdx.x / ROWBLKS;          // 0..BCHUNKS-1
    const int row = rowblk * BLK + t;
    const int cbase = c * CHUNK;

    __shared__ float4 cand[CHUNK];
    cand[t] = sm4[cbase + t];

    float4 p = sm4[row];
    float n2x = -2.0f * p.x, n2y = -2.0f * p.y, n2z = -2.0f * p.z;
    float sp = p.w;
    __syncthreads();

    unsigned s[KSEL];
#pragma unroll
    for (int k = 0; k < KSEL; ++k) s[k] = 0xFFFFFFFFu;

#pragma unroll 8
    for (int j = 0; j < CHUNK; ++j) {
        float4 q = cand[j];
        float d2 = fmaf(n2x, q.x, fmaf(n2y, q.y, fmaf(n2z, q.z, sp + q.w)));
        insert9(s, pack_d2(d2, cbase + j));
    }
    atomicMin(&bound[row], s[0]);   // s[0] = 9th smallest of this chunk
}

// ---------------------------------------------------------------------------
// Kernel 3: filter. Full rescan at ~12 inst/candidate; survivors (x <= bound,
// inclusive) appended to the PRIVATE (row,chunk) segment with a register
// counter — no atomics. Layout surv[(c*CAP+k)*NSAMPLE+row]: stores for fixed
// (c,k) are contiguous across lanes.
// ---------------------------------------------------------------------------
__global__ __launch_bounds__(BLK) void filter_k(
    const float4* __restrict__ sm4, const unsigned* __restrict__ bound,
    unsigned* __restrict__ cnt, unsigned* __restrict__ surv)
{
    const int t = threadIdx.x;
    const int rowblk = blockIdx.x & (ROWBLKS - 1);
    const int c = blockIdx.x / ROWBLKS;          // 0..FCHUNKS-1
    const int row = rowblk * BLK + t;
    const int cbase = c * CHUNK;

    __shared__ float4 cand[CHUNK];
    cand[t] = sm4[cbase + t];

    float4 p = sm4[row];
    float n2x = -2.0f * p.x, n2y = -2.0f * p.y, n2z = -2.0f * p.z;
    float sp = p.w;
    unsigned b = bound[row];
    unsigned* rowsurv = surv + (size_t)c * CAP * NSAMPLE + row;
    unsigned nloc = 0;
    __syncthreads();

#pragma unroll 8
    for (int j = 0; j < CHUNK; ++j) {
        float4 q = cand[j];
        float d2 = fmaf(n2x, q.x, fmaf(n2y, q.y, fmaf(n2z, q.z, sp + q.w)));
        unsigned x = pack_d2(d2, cbase + j);
        if (x <= b) {
            if (nloc < CAP) rowsurv[(size_t)nloc * NSAMPLE] = x;
            ++nloc;
        }
    }
    cnt[c * NSAMPLE + row] = umn(nloc, CAP);
}

// ---------------------------------------------------------------------------
// Kernel 4: select + loss. 8 threads per row: each merges 4 chunks' segments
// into a top-9, LDS-merge 72 entries per row, epilogue, block-reduce, one
// atomicAdd per block. Grid = 64K threads = 1024 waves (good occupancy).
// ---------------------------------------------------------------------------
__global__ __launch_bounds__(BLK) void select_k(
    const unsigned* __restrict__ surv, const unsigned* __restrict__ cnt,
    const float4* __restrict__ sm4, const float4* __restrict__ ss4,
    float* __restrict__ out)
{
    const int t = threadIdx.x;
    const int rowin = t & (ROWS_PB - 1);
    const int sub = t >> 5;                      // 0..7
    const int r = blockIdx.x * ROWS_PB + rowin;

    __shared__ unsigned lds[ROWS_PB * LROW];
    __shared__ float red[ROWS_PB];

    unsigned s[KSEL];
#pragma unroll
    for (int k = 0; k < KSEL; ++k) s[k] = 0xFFFFFFFFu;

#pragma unroll
    for (int ci = 0; ci < CPT; ++ci) {
        int c = sub * CPT + ci;
        unsigned n = cnt[c * NSAMPLE + r];       // coalesced across lanes
        const unsigned* base = surv + (size_t)c * CAP * NSAMPLE + r;
        for (unsigned k = 0; k < n; ++k)
            insert9(s, base[(size_t)k * NSAMPLE]);   // coalesced across lanes
    }
#pragma unroll
    for (int k = 0; k < KSEL; ++k)
        lds[rowin * LROW + sub * KSEL + k] = s[k];
    __syncthreads();

    // Phase 2: lanes with (t&7)==0 each rebuild a fresh top-9 from one row's
    // 72 entries (all distinct candidates; sentinels pushed out since every
    // row stores >= 9 real survivors), then compute the loss terms.
    if ((t & 7) == 0) {
        const int rowh = t >> 3;                 // 0..31
        const int rr = blockIdx.x * ROWS_PB + rowh;
        unsigned m[KSEL];
#pragma unroll
        for (int k = 0; k < KSEL; ++k) m[k] = 0xFFFFFFFFu;
#pragma unroll
        for (int e = 0; e < SUBS * KSEL; ++e)
            insert9(m, lds[rowh * LROW + e]);

        // m[8] = global min (self, or identical-coordinate dup whose term is
        // 0 either way) -> dropped. m[0..7] = the 8 neighbors.
        float4 pm = sm4[rr];
        float4 ps = ss4[rr];
        float acc = 0.0f;
#pragma unroll
        for (int k = 0; k < KNN; ++k) {
            int j = (int)(m[k] & IDX_MASK);
            float4 qm = sm4[j];
            float dx = pm.x - qm.x, dy = pm.y - qm.y, dz = pm.z - qm.z;
            float d2 = fmaf(dx, dx, fmaf(dy, dy, dz * dz));
            float d = sqrtf(fmaxf(d2, EPS_F));
            float w = expf(-d);
            float4 qs = ss4[j];
            float ax = ps.x - qs.x, ay = ps.y - qs.y, az = ps.z - qs.z;
            acc += w * (ax * ax + ay * ay + az * az);
        }
        red[rowh] = acc;
    }
    __syncthreads();
    if (t == 0) {
        float ssum = 0.0f;
#pragma unroll
        for (int i = 0; i < ROWS_PB; ++i) ssum += red[i];
        atomicAdd(out, ssum * SCALE);
    }
}

// ---------------------------------------------------------------------------
extern "C" void kernel_launch(void* const* d_in, const int* in_sizes, int n_in,
                              void* d_out, int out_size, void* d_ws, size_t ws_size,
                              hipStream_t stream)
{
    const float* means = (const float*)d_in[0];
    const float* sh0   = (const float*)d_in[1];
    const int*   idx   = (const int*)d_in[2];

    char* ws = (char*)d_ws;
    float4*   sm4   = (float4*)ws;                              // 128 KB
    float4*   ss4   = (float4*)(ws + NSAMPLE * 16);             // 128 KB
    unsigned* bound = (unsigned*)(ws + 2 * NSAMPLE * 16);       // 32 KB
    unsigned* cnt   = bound + NSAMPLE;                          // 32*8192*4 = 1 MB
    unsigned* surv  = cnt + FCHUNKS * NSAMPLE;                  // 32*24*8192*4 = 24 MB

    gather_k<<<NSAMPLE / BLK, BLK, 0, stream>>>(means, sh0, idx, sm4, ss4,
                                                bound, (float*)d_out);
    bound_k<<<BCHUNKS * ROWBLKS, BLK, 0, stream>>>(sm4, bound);
    filter_k<<<FCHUNKS * ROWBLKS, BLK, 0, stream>>>(sm4, bound, cnt, surv);
    select_k<<<NSAMPLE / ROWS_PB, BLK, 0, stream>>>(surv, cnt, sm4, ss4,
                                                    (float*)d_out);
}